// Round 2
// baseline (1075.459 us; speedup 1.0000x reference)
//
#include <hip/hip_runtime.h>
#include <hip/hip_bf16.h>
#include <math.h>

// ---------------- constants (from reference) ----------------
#define F_IN   336
#define HC     200      // H*C
#define Cch    100      // channels per head
#define SLOPE  0.2f
#define SCAN_BS 256

// padded dims for MFMA GEMM
#define NPAD   224      // HC padded to 14*16
#define KP0    352      // F_IN padded to mult of 32
#define KP1    224      // HC padded to mult of 32

using short8   = __attribute__((ext_vector_type(8))) short;
using float4v  = __attribute__((ext_vector_type(4))) float;
using ushort4v = __attribute__((ext_vector_type(4))) unsigned short;
using float2v  = __attribute__((ext_vector_type(2))) float;

// ---------------- bf16 split helpers ----------------
__device__ inline unsigned short rne_bf16(float v) {
    unsigned int u = __float_as_uint(v);
    return (unsigned short)((u + 0x7fffu + ((u >> 16) & 1u)) >> 16);
}
__device__ inline void split_bf(float v, unsigned short& hi, unsigned short& lo) {
    hi = rne_bf16(v);
    float hv = __uint_as_float(((unsigned int)hi) << 16);
    lo = rne_bf16(v - hv);
}

// monotone uint encoding of float for atomicMax (R12: global es-max)
__device__ inline unsigned int enc_f32(float f) {
    unsigned int u = __float_as_uint(f);
    return (u & 0x80000000u) ? ~u : (u | 0x80000000u);
}
__device__ inline float dec_f32(unsigned int e) {
    return __uint_as_float((e & 0x80000000u) ? (e ^ 0x80000000u) : ~e);
}

// ---------------- CSR build ----------------
__global__ void init_deg(int* deg, unsigned int* gmax, int n) {
    int i = blockIdx.x * 256 + threadIdx.x;
    if (i < n) deg[i] = 1;   // self-loop
    if (i < 10) gmax[i] = 0x007FFFFFu;   // enc(-inf): 5 layers x 2 heads
}

__global__ void count_deg(const int* __restrict__ dst, int* deg, int e) {
    int i = blockIdx.x * 256 + threadIdx.x;
    if (i < e) atomicAdd(&deg[dst[i]], 1);
}

__global__ void scan_block(const int* __restrict__ deg, int* incl, int* bsums, int n) {
    __shared__ int sm[SCAN_BS];
    int i = blockIdx.x * SCAN_BS + threadIdx.x;
    int v = (i < n) ? deg[i] : 0;
    sm[threadIdx.x] = v;
    __syncthreads();
    for (int off = 1; off < SCAN_BS; off <<= 1) {
        int t = (threadIdx.x >= off) ? sm[threadIdx.x - off] : 0;
        __syncthreads();
        sm[threadIdx.x] += t;
        __syncthreads();
    }
    if (i < n) incl[i] = sm[threadIdx.x];
    if (threadIdx.x == SCAN_BS - 1) bsums[blockIdx.x] = sm[threadIdx.x];
}

__global__ void scan_sums(int* bsums, int nb) {
    __shared__ int sm[SCAN_BS];
    int v = (threadIdx.x < nb) ? bsums[threadIdx.x] : 0;
    sm[threadIdx.x] = v;
    __syncthreads();
    for (int off = 1; off < SCAN_BS; off <<= 1) {
        int t = (threadIdx.x >= off) ? sm[threadIdx.x - off] : 0;
        __syncthreads();
        sm[threadIdx.x] += t;
        __syncthreads();
    }
    if (threadIdx.x < nb) bsums[threadIdx.x] = sm[threadIdx.x] - v;  // exclusive
}

__global__ void scan_final(const int* __restrict__ incl, const int* __restrict__ deg,
                           const int* __restrict__ bsums, int* row_ptr, int* cursor, int n) {
    int i = blockIdx.x * SCAN_BS + threadIdx.x;
    if (i < n) {
        int inc = incl[i] + bsums[i / SCAN_BS];
        int ex  = inc - deg[i];
        row_ptr[i] = ex;
        cursor[i]  = ex;
        if (i == n - 1) row_ptr[n] = inc;
    }
}

__global__ void fill_csr(const int* __restrict__ src, const int* __restrict__ dst,
                         int* cursor, int* col_src, int e, int n) {
    int i = blockIdx.x * 256 + threadIdx.x;
    int te = e + n;
    if (i >= te) return;
    int s, d;
    if (i < e) { s = src[i]; d = dst[i]; }
    else       { s = i - e;  d = i - e; }
    int pos = atomicAdd(&cursor[d], 1);
    col_src[pos] = s;
}

// ---------------- split conversions ----------------
__global__ void conv_x(const float* __restrict__ x, unsigned short* __restrict__ Ah,
                       unsigned short* __restrict__ Al, int n_nodes) {
    const int GPR = KP0 / 4;   // 88 groups per row
    int i = blockIdx.x * 256 + threadIdx.x;
    int tot = n_nodes * GPR;
    if (i >= tot) return;
    int row = i / GPR, g4 = i - row * GPR;
    int col = g4 * 4;
    float4v v = {0.f, 0.f, 0.f, 0.f};
    if (col < F_IN) v = *(const float4v*)(x + (size_t)row * F_IN + col);
    ushort4v hv, lv;
    split_bf(v.x, ((unsigned short*)&hv)[0], ((unsigned short*)&lv)[0]);
    split_bf(v.y, ((unsigned short*)&hv)[1], ((unsigned short*)&lv)[1]);
    split_bf(v.z, ((unsigned short*)&hv)[2], ((unsigned short*)&lv)[2]);
    split_bf(v.w, ((unsigned short*)&hv)[3], ((unsigned short*)&lv)[3]);
    size_t b = (size_t)row * KP0 + col;
    *(ushort4v*)(Ah + b) = hv;
    *(ushort4v*)(Al + b) = lv;
}

// all 5 layers' weights split in ONE dispatch, layer-concatenated layout:
// [L0: NPAD*KP0][L1..L4: NPAD*KP1 each]   (R11: 5 dispatches -> 1)
__global__ void conv_w_all(const float* __restrict__ W0, const float* __restrict__ W1,
                           const float* __restrict__ W2, const float* __restrict__ W3,
                           const float* __restrict__ W4,
                           unsigned short* __restrict__ Bh, unsigned short* __restrict__ Bl) {
    const int SZ0 = NPAD * KP0, SZ = NPAD * KP1;
    const int TOT = SZ0 + 4 * SZ;
    int i = blockIdx.x * 256 + threadIdx.x;
    if (i >= TOT) return;
    const float* W; int Kp, K, idx;
    if (i < SZ0) { W = W0; Kp = KP0; K = F_IN; idx = i; }
    else {
        int j = i - SZ0; int l = j / SZ; idx = j - l * SZ;
        W = (l == 0) ? W1 : (l == 1) ? W2 : (l == 2) ? W3 : W4;
        Kp = KP1; K = HC;
    }
    int n = idx / Kp, k = idx - n * Kp;
    float v = (n < HC && k < K) ? W[(size_t)k * HC + n] : 0.f;
    unsigned short hi, lo;
    split_bf(v, hi, lo);
    Bh[i] = hi; Bl[i] = lo;
}

// ---------------- split-bf16 MFMA GEMM + fused attention scores ----------------
// h[M,200] = A[M,Kp] @ Wt^T ; es/ed[n][head] = sum_c h[n][c]*a{s,d}[c]
// R8/R9 lesson: direct-to-reg and small-block variants both land at the same
// ~10% MfmaUtil plateau but slower overall; this LDS-staged 64x224 block is
// the empirical best structure.
// R13 (counters: MfmaUtil 12%, VALUBusy 11%, HBM 14%, occupancy 17% -> pure
// latency-bound; SQ_LDS_BANK_CONFLICT 4.96M):
//  (a) T14 async-stage: next k-step's 9 dwordx4 global loads issue into regs
//      DURING the MFMA phase; ds_write after the barrier. Hides HBM latency.
//  (b) staging lane remap: consecutive lanes -> consecutive ROWS (same 16B
//      chunk). With 80B row stride, 8-lane groups hit start banks
//      {0,20,8,28,16,4,24,12} -> all 32 banks covered, write conflicts -> 0.
//      (old mapping: 4 lanes/row -> lane0/lane7 both on banks 0-3.)
#define LDK 40   // LDS k-stride (32 + 8 pad); reads 2-way max (free per m136)
__global__ __launch_bounds__(256, 2) void gemm_split(
    const unsigned short* __restrict__ Ah, const unsigned short* __restrict__ Al,
    const unsigned short* __restrict__ Bh, const unsigned short* __restrict__ Bl,
    const float* __restrict__ asrc, const float* __restrict__ adst,
    float* __restrict__ h, float* __restrict__ es, float* __restrict__ ed,
    unsigned int* __restrict__ gmax,
    int M, int Kp)
{
    __shared__ unsigned short As[2][64][LDK];
    __shared__ unsigned short Bs[2][NPAD][LDK];
    __shared__ float sc[64][4];    // es0, es1, ed0, ed1 per block row
    int tid  = threadIdx.x;
    int wave = tid >> 6, lane = tid & 63;
    int quad = lane >> 4, l16 = lane & 15;
    int wm = (wave >> 1) * 32;
    int wn = (wave & 1) * 112;
    int r0 = blockIdx.x * 64;

    ((float*)sc)[tid] = 0.f;   // 64*4 == 256 — one element per thread

    // ---- loop-invariant staging coordinates (R13 lane remap) ----
    // A: 512 uint4 slots = 2 splits x 64 rows x 4 chunks
    int a_s[2], a_row[2], a_kc[2]; bool a_v[2]; size_t a_go[2];
#pragma unroll
    for (int i = 0; i < 2; i++) {
        int c = tid + 256 * i;
        int s = c >> 8, cc = c & 255;
        int row = cc & 63, kc = (cc >> 6) * 8;
        a_s[i] = s; a_row[i] = row; a_kc[i] = kc;
        int gr = r0 + row;
        a_v[i]  = gr < M;
        a_go[i] = (size_t)(a_v[i] ? gr : 0) * Kp + kc;
    }
    // B: 1792 uint4 slots = 2 splits x 224 rows x 4 chunks
    int b_s[7], b_row[7], b_kc[7]; size_t b_go[7];
#pragma unroll
    for (int i = 0; i < 7; i++) {
        int c = tid + 256 * i;
        int s = (c >= 896) ? 1 : 0;
        int cc = c - s * 896;
        int row = cc % 224, kc = (cc / 224) * 8;
        b_s[i] = s; b_row[i] = row; b_kc[i] = kc;
        b_go[i] = (size_t)row * Kp + kc;
    }

    float4v acc[2][7];
#pragma unroll
    for (int mt = 0; mt < 2; mt++)
#pragma unroll
        for (int nt = 0; nt < 7; nt++)
            acc[mt][nt] = (float4v){0.f, 0.f, 0.f, 0.f};

    uint4 ra[2], rb[7];
    // prologue: issue k=0 loads
#pragma unroll
    for (int i = 0; i < 2; i++) {
        const unsigned short* g = a_s[i] ? Al : Ah;
        uint4 v = make_uint4(0u, 0u, 0u, 0u);
        if (a_v[i]) v = *(const uint4*)(g + a_go[i]);
        ra[i] = v;
    }
#pragma unroll
    for (int i = 0; i < 7; i++) {
        const unsigned short* g = b_s[i] ? Bl : Bh;
        rb[i] = *(const uint4*)(g + b_go[i]);
    }

    for (int k0 = 0; k0 < Kp; k0 += 32) {
        __syncthreads();   // prior k-step's readers done (also drains vmem)
#pragma unroll
        for (int i = 0; i < 2; i++)
            *(uint4*)&As[a_s[i]][a_row[i]][a_kc[i]] = ra[i];
#pragma unroll
        for (int i = 0; i < 7; i++)
            *(uint4*)&Bs[b_s[i]][b_row[i]][b_kc[i]] = rb[i];
        __syncthreads();

        // issue NEXT k-step's loads; latency hides under the MFMAs below
        int kn = k0 + 32;
        if (kn < Kp) {
#pragma unroll
            for (int i = 0; i < 2; i++) {
                const unsigned short* g = a_s[i] ? Al : Ah;
                uint4 v = make_uint4(0u, 0u, 0u, 0u);
                if (a_v[i]) v = *(const uint4*)(g + a_go[i] + kn);
                ra[i] = v;
            }
#pragma unroll
            for (int i = 0; i < 7; i++) {
                const unsigned short* g = b_s[i] ? Bl : Bh;
                rb[i] = *(const uint4*)(g + b_go[i] + kn);
            }
        }

        short8 a_h[2], a_l[2];
#pragma unroll
        for (int mt = 0; mt < 2; mt++) {
            a_h[mt] = *(const short8*)&As[0][wm + mt * 16 + l16][quad * 8];
            a_l[mt] = *(const short8*)&As[1][wm + mt * 16 + l16][quad * 8];
        }
#pragma unroll
        for (int nt = 0; nt < 7; nt++) {
            short8 b_h = *(const short8*)&Bs[0][wn + nt * 16 + l16][quad * 8];
            short8 b_l = *(const short8*)&Bs[1][wn + nt * 16 + l16][quad * 8];
#pragma unroll
            for (int mt = 0; mt < 2; mt++) {
                acc[mt][nt] = __builtin_amdgcn_mfma_f32_16x16x32_bf16(a_h[mt], b_h, acc[mt][nt], 0, 0, 0);
                acc[mt][nt] = __builtin_amdgcn_mfma_f32_16x16x32_bf16(a_h[mt], b_l, acc[mt][nt], 0, 0, 0);
                acc[mt][nt] = __builtin_amdgcn_mfma_f32_16x16x32_bf16(a_l[mt], b_h, acc[mt][nt], 0, 0, 0);
            }
        }
    }

    // per-lane per-nt score weights (uniform loads, cached)
    float asc[7], adc[7];
    bool  vld[7];
    bool  hd1[7];
#pragma unroll
    for (int nt = 0; nt < 7; nt++) {
        int col = wn + nt * 16 + l16;
        vld[nt] = col < HC;
        hd1[nt] = col >= Cch;
        asc[nt] = vld[nt] ? asrc[col] : 0.f;
        adc[nt] = vld[nt] ? adst[col] : 0.f;
    }

    // epilogue: write h + accumulate score partials
#pragma unroll
    for (int mt = 0; mt < 2; mt++) {
        float p[4][4];
#pragma unroll
        for (int r = 0; r < 4; r++)
#pragma unroll
            for (int t = 0; t < 4; t++) p[r][t] = 0.f;
#pragma unroll
        for (int nt = 0; nt < 7; nt++) {
            int col = wn + nt * 16 + l16;
#pragma unroll
            for (int r = 0; r < 4; r++) {
                float v = acc[mt][nt][r];
                int grow = r0 + wm + mt * 16 + quad * 4 + r;
                if (vld[nt] && grow < M) h[(size_t)grow * HC + col] = v;
                float va = v * asc[nt], vd = v * adc[nt];
                p[r][0] += hd1[nt] ? 0.f : va;
                p[r][1] += hd1[nt] ? va  : 0.f;
                p[r][2] += hd1[nt] ? 0.f : vd;
                p[r][3] += hd1[nt] ? vd  : 0.f;
            }
        }
#pragma unroll
        for (int off = 1; off < 16; off <<= 1)
#pragma unroll
            for (int r = 0; r < 4; r++)
#pragma unroll
                for (int t = 0; t < 4; t++)
                    p[r][t] += __shfl_xor(p[r][t], off);
        if (l16 == 0) {
            int lrow = wm + mt * 16 + quad * 4;
#pragma unroll
            for (int r = 0; r < 4; r++)
#pragma unroll
                for (int t = 0; t < 4; t++)
                    atomicAdd(&sc[lrow + r][t], p[r][t]);
        }
    }
    __syncthreads();
    if (tid < 64) {
        int grow = r0 + tid;
        float e0v = sc[tid][0], e1v = sc[tid][1];
        if (grow < M) {
            es[grow * 2 + 0] = e0v;
            es[grow * 2 + 1] = e1v;
            ed[grow * 2 + 0] = sc[tid][2];
            ed[grow * 2 + 1] = sc[tid][3];
        }
        // block es-max -> global per-layer max (pad rows contribute 0 from
        // zeroed A rows: still a valid UPPER bound, only shrinks exp args)
#pragma unroll
        for (int off = 1; off < 64; off <<= 1) {
            e0v = fmaxf(e0v, __shfl_xor(e0v, off));
            e1v = fmaxf(e1v, __shfl_xor(e1v, off));
        }
        if (tid == 0) {
            atomicMax(&gmax[0], enc_f32(e0v));
            atomicMax(&gmax[1], enc_f32(e1v));
        }
    }
}

// ---------------- fused softmax + weighted gather (wave per dst node) ----------------
// R12: SINGLE pass. Instead of a per-node max pass, use the per-layer global
// es-max: m_node <= leaky(es_gmax + ed_node) (leaky is monotone), and a softmax
// shift by any upper bound leaves alpha = p/sum(p) unchanged. p <= 1 guaranteed;
// sum(p) shrinks by exp(m_true - bound) ~ e^-few, so epsilon lowered to 1e-33.
// (R5 lesson: shfls in uniform control flow only.)
template<bool WF, bool WB>
__global__ __launch_bounds__(256) void gat_gather(
    const float* __restrict__ h, const float* __restrict__ es, const float* __restrict__ ed,
    const unsigned int* __restrict__ gmax,
    const int* __restrict__ row_ptr, const int* __restrict__ col_src,
    const float* __restrict__ bias, float* __restrict__ outF,
    unsigned short* __restrict__ oh, unsigned short* __restrict__ ol, int n_nodes)
{
    int wave = threadIdx.x >> 6, lane = threadIdx.x & 63;
    int n = blockIdx.x * 4 + wave;
    if (n >= n_nodes) return;
    int e0 = row_ptr[n], e1 = row_ptr[n + 1];
    bool act  = lane < 50;
    int  hsel = (lane >= 25) ? 1 : 0;
    float ed0 = ed[n * 2], ed1 = ed[n * 2 + 1];
    float gm0 = dec_f32(gmax[0]), gm1 = dec_f32(gmax[1]);
    float t0 = gm0 + ed0, t1 = gm1 + ed1;
    float mb0 = t0 > 0.f ? t0 : SLOPE * t0;   // upper bound on per-node max
    float mb1 = t1 > 0.f ? t1 : SLOPE * t1;

    // ---- single pass: p = exp(s-mb), accumulate l, gather with unnormalized p ----
    float l0 = 0.f, l1 = 0.f;
    float4v a0 = {0.f, 0.f, 0.f, 0.f}, a1 = {0.f, 0.f, 0.f, 0.f};
    float4v a2 = {0.f, 0.f, 0.f, 0.f}, a3 = {0.f, 0.f, 0.f, 0.f};

    for (int cbase = e0; cbase < e1; cbase += 64) {
        int cnt = e1 - cbase; if (cnt > 64) cnt = 64;
        int   sidx = 0;
        float px = 0.f, py = 0.f;
        if (lane < cnt) {
            sidx = col_src[cbase + lane];
            float2v q = *(const float2v*)&es[sidx * 2];
            float s0 = q.x + ed0, s1 = q.y + ed1;
            s0 = s0 > 0.f ? s0 : SLOPE * s0;
            s1 = s1 > 0.f ? s1 : SLOPE * s1;
            px = __expf(s0 - mb0);
            py = __expf(s1 - mb1);
            l0 += px; l1 += py;
        }
        int j = 0;
        for (; j + 4 <= cnt; j += 4) {
            int s0 = __shfl(sidx, j + 0), s1 = __shfl(sidx, j + 1);
            int s2 = __shfl(sidx, j + 2), s3 = __shfl(sidx, j + 3);
            float x0 = __shfl(px, j + 0), y0 = __shfl(py, j + 0);
            float x1 = __shfl(px, j + 1), y1 = __shfl(py, j + 1);
            float x2 = __shfl(px, j + 2), y2 = __shfl(py, j + 2);
            float x3 = __shfl(px, j + 3), y3 = __shfl(py, j + 3);
            float p0 = hsel ? y0 : x0;
            float p1 = hsel ? y1 : x1;
            float p2 = hsel ? y2 : x2;
            float p3 = hsel ? y3 : x3;
            if (act) {
                float4v v0 = *(const float4v*)(h + (size_t)s0 * HC + lane * 4);
                float4v v1 = *(const float4v*)(h + (size_t)s1 * HC + lane * 4);
                float4v v2 = *(const float4v*)(h + (size_t)s2 * HC + lane * 4);
                float4v v3 = *(const float4v*)(h + (size_t)s3 * HC + lane * 4);
                a0.x += p0 * v0.x; a0.y += p0 * v0.y; a0.z += p0 * v0.z; a0.w += p0 * v0.w;
                a1.x += p1 * v1.x; a1.y += p1 * v1.y; a1.z += p1 * v1.z; a1.w += p1 * v1.w;
                a2.x += p2 * v2.x; a2.y += p2 * v2.y; a2.z += p2 * v2.z; a2.w += p2 * v2.w;
                a3.x += p3 * v3.x; a3.y += p3 * v3.y; a3.z += p3 * v3.z; a3.w += p3 * v3.w;
            }
        }
        for (; j < cnt; j++) {
            int s0 = __shfl(sidx, j);
            float x0 = __shfl(px, j), y0 = __shfl(py, j);
            float p0 = hsel ? y0 : x0;
            if (act) {
                float4v v0 = *(const float4v*)(h + (size_t)s0 * HC + lane * 4);
                a0.x += p0 * v0.x; a0.y += p0 * v0.y; a0.z += p0 * v0.z; a0.w += p0 * v0.w;
            }
        }
    }
#pragma unroll
    for (int off = 1; off < 64; off <<= 1) {
        l0 += __shfl_xor(l0, off);
        l1 += __shfl_xor(l1, off);
    }

    float4v acc;
    acc.x = (a0.x + a1.x) + (a2.x + a3.x);
    acc.y = (a0.y + a1.y) + (a2.y + a3.y);
    acc.z = (a0.z + a1.z) + (a2.z + a3.z);
    acc.w = (a0.w + a1.w) + (a2.w + a3.w);

    float li = 1.f / ((hsel ? l1 : l0) + 1e-33f);
    if (act) {
        float4v bb = *(const float4v*)(bias + lane * 4);
        float4v r;
        r.x = fmaxf(acc.x * li + bb.x, 0.f);
        r.y = fmaxf(acc.y * li + bb.y, 0.f);
        r.z = fmaxf(acc.z * li + bb.z, 0.f);
        r.w = fmaxf(acc.w * li + bb.w, 0.f);
        if (WF) {
            __builtin_nontemporal_store(r, (float4v*)(outF + (size_t)n * HC + lane * 4));
        }
        if (WB) {
            ushort4v hv, lv;
            split_bf(r.x, ((unsigned short*)&hv)[0], ((unsigned short*)&lv)[0]);
            split_bf(r.y, ((unsigned short*)&hv)[1], ((unsigned short*)&lv)[1]);
            split_bf(r.z, ((unsigned short*)&hv)[2], ((unsigned short*)&lv)[2]);
            split_bf(r.w, ((unsigned short*)&hv)[3], ((unsigned short*)&lv)[3]);
            size_t b = (size_t)n * NPAD + lane * 4;
            __builtin_nontemporal_store(hv, (ushort4v*)(oh + b));
            __builtin_nontemporal_store(lv, (ushort4v*)(ol + b));
        }
    } else if (WB && lane < 56) {   // zero pad cols 200..223
        ushort4v z = {0, 0, 0, 0};
        size_t b = (size_t)n * NPAD + lane * 4;
        __builtin_nontemporal_store(z, (ushort4v*)(oh + b));
        __builtin_nontemporal_store(z, (ushort4v*)(ol + b));
    }
}

// ---------------- pooling ----------------
// graph_bounds + pool_zero merged (independent index ranges, one grid) (R11)
__global__ void bounds_zero(const int* __restrict__ batch, int* gstart,
                            float* pool, int n, int g) {
    int i = blockIdx.x * 256 + threadIdx.x;
    if (i < g * HC) pool[i] = 0.f;
    if (i >= n) return;
    int b = batch[i];
    int bp = (i == 0) ? -1 : batch[i - 1];
    for (int q = bp + 1; q <= b; q++) gstart[q] = i;
    if (i == n - 1) for (int q = b + 1; q <= g; q++) gstart[q] = n;
}

__global__ __launch_bounds__(256) void pool_part(
    const float* __restrict__ x, const int* __restrict__ batch,
    float* __restrict__ pool, int n_nodes)
{
    int wave = threadIdx.x >> 6, lane = threadIdx.x & 63;
    int base = (blockIdx.x * 4 + wave) * 16;
    if (base >= n_nodes) return;
    bool act = lane < 50;
    int end = base + 16; if (end > n_nodes) end = n_nodes;
    float4v acc = {0.f, 0.f, 0.f, 0.f};
    int curg = batch[base];
    for (int n = base; n < end; n++) {
        int g = batch[n];
        if (g != curg) {
            if (act) {
                float* pp = pool + (size_t)curg * HC + lane * 4;
                atomicAdd(pp + 0, acc.x); atomicAdd(pp + 1, acc.y);
                atomicAdd(pp + 2, acc.z); atomicAdd(pp + 3, acc.w);
            }
            acc = (float4v){0.f, 0.f, 0.f, 0.f};
            curg = g;
        }
        if (act) {
            float4v v = *(const float4v*)(x + (size_t)n * HC + lane * 4);
            acc.x += v.x; acc.y += v.y; acc.z += v.z; acc.w += v.w;
        }
    }
    if (act) {
        float* pp = pool + (size_t)curg * HC + lane * 4;
        atomicAdd(pp + 0, acc.x); atomicAdd(pp + 1, acc.y);
        atomicAdd(pp + 2, acc.z); atomicAdd(pp + 3, acc.w);
    }
}

// ---------------- fused MLP head: pool-divide + 3 layers, one dispatch (R11) ----------------
__global__ __launch_bounds__(128) void mlp_head(
    const float* __restrict__ pool, const int* __restrict__ gstart,
    const float* __restrict__ lw1, const float* __restrict__ lb1,
    const float* __restrict__ lw2, const float* __restrict__ lb2,
    const float* __restrict__ lw3, const float* __restrict__ lb3,
    float* __restrict__ out)
{
    __shared__ float xa[200];
    __shared__ float xb[100];
    __shared__ float xc[100];
    int g = blockIdx.x, t = threadIdx.x;
    float inv = 1.f / fmaxf((float)(gstart[g + 1] - gstart[g]), 1.f);
    for (int k = t; k < 200; k += 128) xa[k] = pool[g * 200 + k] * inv;
    __syncthreads();
    if (t < 100) {
        float s = lb1[t];
        for (int k = 0; k < 200; k++) s = fmaf(xa[k], lw1[k * 100 + t], s);
        xb[t] = fmaxf(s, 0.f);
    }
    __syncthreads();
    if (t < 100) {
        float s = lb2[t];
        for (int k = 0; k < 100; k++) s = fmaf(xb[k], lw2[k * 100 + t], s);
        xc[t] = fmaxf(s, 0.f);
    }
    __syncthreads();
    if (t < 29) {
        float s = lb3[t];
        for (int k = 0; k < 100; k++) s = fmaf(xc[k], lw3[k * 29 + t], s);
        out[g * 29 + t] = s;
    }
}

// ---------------- launch ----------------
extern "C" void kernel_launch(void* const* d_in, const int* in_sizes, int n_in,
                              void* d_out, int out_size, void* d_ws, size_t ws_size,
                              hipStream_t stream) {
    const float* x     = (const float*)d_in[0];
    const int*   ei    = (const int*)d_in[1];
    const int*   batch = (const int*)d_in[2];
    const float *W[5], *asrc[5], *adst[5], *bc[5];
    for (int i = 0; i < 5; i++) {
        W[i]    = (const float*)d_in[3 + i * 4];
        asrc[i] = (const float*)d_in[4 + i * 4];
        adst[i] = (const float*)d_in[5 + i * 4];
        bc[i]   = (const float*)d_in[6 + i * 4];
    }
    const float* lw1 = (const float*)d_in[23];
    const float* lb1 = (const float*)d_in[24];
    const float* lw2 = (const float*)d_in[25];
    const float* lb2 = (const float*)d_in[26];
    const float* lw3 = (const float*)d_in[27];
    const float* lb3 = (const float*)d_in[28];
    float* out = (float*)d_out;

    const int N  = in_sizes[0] / F_IN;
    const int E  = in_sizes[1] / 2;
    const int G  = out_size / 29;
    const int TE = E + N;
    const int* esrc = ei;
    const int* edst = ei + E;

    const int WSZ0 = NPAD * KP0;          // layer-0 split-weight size
    const int WSZ  = NPAD * KP1;          // layers 1-4
    const int WTOT = WSZ0 + 4 * WSZ;

    // workspace carve
    char* p = (char*)d_ws;
    auto carve = [&](size_t bytes) { void* r = (void*)p; p += ((bytes + 255) / 256) * 256; return r; };
    float*          hbuf = (float*)carve((size_t)N * HC * 4);          // GEMM out h (fp32)
    unsigned short* Ah   = (unsigned short*)carve((size_t)N * KP0 * 2);
    unsigned short* Al   = (unsigned short*)carve((size_t)N * KP0 * 2);
    float*          outF = (float*)Ah;  // aliases Ah/Al (dead by the time L5 gather writes)
    unsigned short* Wth  = (unsigned short*)carve((size_t)WTOT * 2);
    unsigned short* Wtl  = (unsigned short*)carve((size_t)WTOT * 2);
    float* es_     = (float*)carve((size_t)N * 2 * 4);
    float* ed_     = (float*)carve((size_t)N * 2 * 4);
    unsigned int* gmax5 = (unsigned int*)carve(10 * 4);   // 5 layers x 2 heads es-max
    int*   deg     = (int*)carve((size_t)N * 4);
    int*   incl    = (int*)carve((size_t)N * 4);
    int*   bsums   = (int*)carve(SCAN_BS * 4);
    int*   row_ptr = (int*)carve((size_t)(N + 1) * 4);
    int*   cursor  = (int*)carve((size_t)N * 4);
    int*   col_src = (int*)carve((size_t)TE * 4);
    int*   gstart  = (int*)carve((size_t)(G + 1) * 4);
    float* pool    = (float*)carve((size_t)G * HC * 4);

    const int nBlkN   = (N + 255) / 256;
    const int nBlkE   = (E + 255) / 256;
    const int nBlkTE  = (TE + 255) / 256;
    const int nScanB  = (N + SCAN_BS - 1) / SCAN_BS;
    const int nWaveB  = (N + 3) / 4;
    const int nGemmB  = (N + 63) / 64;
    const int nPoolB  = (N + 63) / 64;
    const int nBZ     = (((N > G * HC) ? N : G * HC) + 255) / 256;

    // ---- CSR build ----
    init_deg<<<nBlkN, 256, 0, stream>>>(deg, gmax5, N);
    count_deg<<<nBlkE, 256, 0, stream>>>(edst, deg, E);
    scan_block<<<nScanB, SCAN_BS, 0, stream>>>(deg, incl, bsums, N);
    scan_sums<<<1, SCAN_BS, 0, stream>>>(bsums, nScanB);
    scan_final<<<nScanB, SCAN_BS, 0, stream>>>(incl, deg, bsums, row_ptr, cursor, N);
    fill_csr<<<nBlkTE, 256, 0, stream>>>(esrc, edst, cursor, col_src, E, N);

    // ---- input + weight splits (once) ----
    conv_x<<<(N * (KP0 / 4) + 255) / 256, 256, 0, stream>>>(x, Ah, Al, N);
    conv_w_all<<<(WTOT + 255) / 256, 256, 0, stream>>>(W[0], W[1], W[2], W[3], W[4], Wth, Wtl);

    // ---- 5 GAT layers ----
    for (int L = 0; L < 5; L++) {
        int Kp   = (L == 0) ? KP0 : KP1;
        int woff = (L == 0) ? 0 : WSZ0 + (L - 1) * WSZ;
        gemm_split<<<nGemmB, 256, 0, stream>>>(Ah, Al, Wth + woff, Wtl + woff,
                                               asrc[L], adst[L], hbuf, es_, ed_,
                                               gmax5 + 2 * L, N, Kp);
        if (L < 4)
            gat_gather<false, true><<<nWaveB, 256, 0, stream>>>(hbuf, es_, ed_, gmax5 + 2 * L,
                                                                row_ptr, col_src,
                                                                bc[L], nullptr, Ah, Al, N);
        else
            gat_gather<true, false><<<nWaveB, 256, 0, stream>>>(hbuf, es_, ed_, gmax5 + 2 * L,
                                                                row_ptr, col_src,
                                                                bc[L], outF, nullptr, nullptr, N);
    }

    // ---- pooling + MLP head ----
    bounds_zero<<<nBZ, 256, 0, stream>>>(batch, gstart, pool, N, G);
    pool_part<<<nPoolB, 256, 0, stream>>>(outF, batch, pool, N);
    mlp_head<<<G, 128, 0, stream>>>(pool, gstart, lw1, lb1, lw2, lb2, lw3, lb3, out);
}

// Round 3
// 835.178 us; speedup vs baseline: 1.2877x; 1.2877x over previous
//
#include <hip/hip_runtime.h>
#include <hip/hip_bf16.h>
#include <math.h>

// ---------------- constants (from reference) ----------------
#define F_IN   336
#define HC     200      // H*C
#define Cch    100      // channels per head
#define SLOPE  0.2f
#define SCAN_BS 256

// padded dims for MFMA GEMM
#define NPAD   224      // HC padded to 14*16
#define KP0    352      // F_IN padded to mult of 32
#define KP1    224      // HC padded to mult of 32

using short8   = __attribute__((ext_vector_type(8))) short;
using float4v  = __attribute__((ext_vector_type(4))) float;
using ushort4v = __attribute__((ext_vector_type(4))) unsigned short;
using float2v  = __attribute__((ext_vector_type(2))) float;

// address-space types for global_load_lds
typedef __attribute__((address_space(1))) const void GASV;
typedef __attribute__((address_space(3))) void LASV;

// ---------------- bf16 split helpers ----------------
__device__ inline unsigned short rne_bf16(float v) {
    unsigned int u = __float_as_uint(v);
    return (unsigned short)((u + 0x7fffu + ((u >> 16) & 1u)) >> 16);
}
__device__ inline void split_bf(float v, unsigned short& hi, unsigned short& lo) {
    hi = rne_bf16(v);
    float hv = __uint_as_float(((unsigned int)hi) << 16);
    lo = rne_bf16(v - hv);
}

// monotone uint encoding of float for atomicMax (R12: global es-max)
__device__ inline unsigned int enc_f32(float f) {
    unsigned int u = __float_as_uint(f);
    return (u & 0x80000000u) ? ~u : (u | 0x80000000u);
}
__device__ inline float dec_f32(unsigned int e) {
    return __uint_as_float((e & 0x80000000u) ? (e ^ 0x80000000u) : ~e);
}

// ---------------- CSR build ----------------
__global__ void init_deg(int* deg, unsigned int* gmax, int n) {
    int i = blockIdx.x * 256 + threadIdx.x;
    if (i < n) deg[i] = 1;   // self-loop
    if (i < 10) gmax[i] = 0x007FFFFFu;   // enc(-inf): 5 layers x 2 heads
}

__global__ void count_deg(const int* __restrict__ dst, int* deg, int e) {
    int i = blockIdx.x * 256 + threadIdx.x;
    if (i < e) atomicAdd(&deg[dst[i]], 1);
}

__global__ void scan_block(const int* __restrict__ deg, int* incl, int* bsums, int n) {
    __shared__ int sm[SCAN_BS];
    int i = blockIdx.x * SCAN_BS + threadIdx.x;
    int v = (i < n) ? deg[i] : 0;
    sm[threadIdx.x] = v;
    __syncthreads();
    for (int off = 1; off < SCAN_BS; off <<= 1) {
        int t = (threadIdx.x >= off) ? sm[threadIdx.x - off] : 0;
        __syncthreads();
        sm[threadIdx.x] += t;
        __syncthreads();
    }
    if (i < n) incl[i] = sm[threadIdx.x];
    if (threadIdx.x == SCAN_BS - 1) bsums[blockIdx.x] = sm[threadIdx.x];
}

__global__ void scan_sums(int* bsums, int nb) {
    __shared__ int sm[SCAN_BS];
    int v = (threadIdx.x < nb) ? bsums[threadIdx.x] : 0;
    sm[threadIdx.x] = v;
    __syncthreads();
    for (int off = 1; off < SCAN_BS; off <<= 1) {
        int t = (threadIdx.x >= off) ? sm[threadIdx.x - off] : 0;
        __syncthreads();
        sm[threadIdx.x] += t;
        __syncthreads();
    }
    if (threadIdx.x < nb) bsums[threadIdx.x] = sm[threadIdx.x] - v;  // exclusive
}

__global__ void scan_final(const int* __restrict__ incl, const int* __restrict__ deg,
                           const int* __restrict__ bsums, int* row_ptr, int* cursor, int n) {
    int i = blockIdx.x * SCAN_BS + threadIdx.x;
    if (i < n) {
        int inc = incl[i] + bsums[i / SCAN_BS];
        int ex  = inc - deg[i];
        row_ptr[i] = ex;
        cursor[i]  = ex;
        if (i == n - 1) row_ptr[n] = inc;
    }
}

__global__ void fill_csr(const int* __restrict__ src, const int* __restrict__ dst,
                         int* cursor, int* col_src, int e, int n) {
    int i = blockIdx.x * 256 + threadIdx.x;
    int te = e + n;
    if (i >= te) return;
    int s, d;
    if (i < e) { s = src[i]; d = dst[i]; }
    else       { s = i - e;  d = i - e; }
    int pos = atomicAdd(&cursor[d], 1);
    col_src[pos] = s;
}

// ---------------- split conversions ----------------
__global__ void conv_x(const float* __restrict__ x, unsigned short* __restrict__ Ah,
                       unsigned short* __restrict__ Al, int n_nodes) {
    const int GPR = KP0 / 4;   // 88 groups per row
    int i = blockIdx.x * 256 + threadIdx.x;
    int tot = n_nodes * GPR;
    if (i >= tot) return;
    int row = i / GPR, g4 = i - row * GPR;
    int col = g4 * 4;
    float4v v = {0.f, 0.f, 0.f, 0.f};
    if (col < F_IN) v = *(const float4v*)(x + (size_t)row * F_IN + col);
    ushort4v hv, lv;
    split_bf(v.x, ((unsigned short*)&hv)[0], ((unsigned short*)&lv)[0]);
    split_bf(v.y, ((unsigned short*)&hv)[1], ((unsigned short*)&lv)[1]);
    split_bf(v.z, ((unsigned short*)&hv)[2], ((unsigned short*)&lv)[2]);
    split_bf(v.w, ((unsigned short*)&hv)[3], ((unsigned short*)&lv)[3]);
    size_t b = (size_t)row * KP0 + col;
    *(ushort4v*)(Ah + b) = hv;
    *(ushort4v*)(Al + b) = lv;
}

// all 5 layers' weights split in ONE dispatch, layer-concatenated layout:
// [L0: NPAD*KP0][L1..L4: NPAD*KP1 each]   (R11: 5 dispatches -> 1)
__global__ void conv_w_all(const float* __restrict__ W0, const float* __restrict__ W1,
                           const float* __restrict__ W2, const float* __restrict__ W3,
                           const float* __restrict__ W4,
                           unsigned short* __restrict__ Bh, unsigned short* __restrict__ Bl) {
    const int SZ0 = NPAD * KP0, SZ = NPAD * KP1;
    const int TOT = SZ0 + 4 * SZ;
    int i = blockIdx.x * 256 + threadIdx.x;
    if (i >= TOT) return;
    const float* W; int Kp, K, idx;
    if (i < SZ0) { W = W0; Kp = KP0; K = F_IN; idx = i; }
    else {
        int j = i - SZ0; int l = j / SZ; idx = j - l * SZ;
        W = (l == 0) ? W1 : (l == 1) ? W2 : (l == 2) ? W3 : W4;
        Kp = KP1; K = HC;
    }
    int n = idx / Kp, k = idx - n * Kp;
    float v = (n < HC && k < K) ? W[(size_t)k * HC + n] : 0.f;
    unsigned short hi, lo;
    split_bf(v, hi, lo);
    Bh[i] = hi; Bl[i] = lo;
}

// ---------------- split-bf16 MFMA GEMM + fused attention scores ----------------
// h[M,200] = A[M,Kp] @ Wt^T ; es/ed[n][head] = sum_c h[n][c]*a{s,d}[c]
// R13 post-mortem: register prefetch spilled to scratch (WRITE_SIZE 40->180MB)
// -> 2x slower. Registers may NOT hold prefetch across barriers/back-edge.
// R14: T3 minimal 2-phase with global_load_lds (DMA, zero regs held):
//   - double-buffered LINEAR LDS tiles [row][32hw]; DMA writes lane*16B
//     contiguous (no ds_write, no write conflicts, no pad possible)
//   - read-side 16B-chunk XOR swizzle  phys = quad ^ ((row>>1)&3)  and the
//     SAME involution pre-applied to the per-lane GLOBAL source (rule #21)
//     -> 2-way read conflicts (free per m136)
//   - iteration t: DMA tile t+1 into buf^1, ds_read+MFMA on buf, ONE
//     __syncthreads() (its implicit vmcnt(0) drain = the wait, issued ~400cy
//     earlier under the MFMAs)
//   - OOB A rows: source clamped (garbage rows), excluded from es-max.
#define LBUF 18432   // halfwords per LDS stage: A 2x64x32 (4096) + B 2x224x32 (14336)
__global__ __launch_bounds__(256, 2) void gemm_split(
    const unsigned short* __restrict__ Ah, const unsigned short* __restrict__ Al,
    const unsigned short* __restrict__ Bh, const unsigned short* __restrict__ Bl,
    const float* __restrict__ asrc, const float* __restrict__ adst,
    float* __restrict__ h, float* __restrict__ es, float* __restrict__ ed,
    unsigned int* __restrict__ gmax,
    int M, int Kp)
{
    __shared__ unsigned short Ls[2][LBUF];
    __shared__ float sc[64][4];    // es0, es1, ed0, ed1 per block row
    int tid  = threadIdx.x;
    int wave = tid >> 6, lane = tid & 63;
    int quad = lane >> 4, l16 = lane & 15;
    int wm = (wave >> 1) * 32;
    int wn = (wave & 1) * 112;
    int r0 = blockIdx.x * 64;

    ((float*)sc)[tid] = 0.f;   // 64*4 == 256 — one element per thread

    // ---- per-lane DMA source pointers (9 chunk-loads of 1KB per wave) ----
    // chunk c (0..35): c<8 -> A split c>>2, rowbase (c&3)*16
    //                  else cb=c-8 -> B split cb/14, rowbase (cb%14)*16
    // lane within chunk: row = rb + (lane>>2); phys 16B slot = lane&3;
    // source fetches LOGICAL slot (lane&3) ^ ((lane>>3)&3)  (inverse swizzle;
    // rowbase multiple of 16 contributes 0 to (row>>1)&3).
    const unsigned short* gp[9];
    unsigned lof[9];
    {
        int r16 = lane >> 2;
        int cl  = (lane & 3) ^ ((lane >> 3) & 3);
#pragma unroll
        for (int j = 0; j < 9; j++) {
            int c = wave * 9 + j;
            if (c < 8) {
                int s = c >> 2, rb = (c & 3) * 16;
                int gr = r0 + rb + r16; if (gr >= M) gr = M - 1;  // clamp (garbage ok)
                gp[j]  = (s ? Al : Ah) + (size_t)gr * Kp + cl * 8;
                lof[j] = s * 2048 + rb * 32;
            } else {
                int cb = c - 8;
                int s = (cb >= 14) ? 1 : 0, rb = (cb - s * 14) * 16;
                gp[j]  = (s ? Bl : Bh) + (size_t)(rb + r16) * Kp + cl * 8;
                lof[j] = 4096 + s * 7168 + rb * 32;
            }
        }
    }

    float4v acc[2][7];
#pragma unroll
    for (int mt = 0; mt < 2; mt++)
#pragma unroll
        for (int nt = 0; nt < 7; nt++)
            acc[mt][nt] = (float4v){0.f, 0.f, 0.f, 0.f};

    // prologue: DMA tile k=0 into buf 0
#pragma unroll
    for (int j = 0; j < 9; j++)
        __builtin_amdgcn_global_load_lds((GASV*)(gp[j]), (LASV*)(&Ls[0][0] + lof[j]), 16, 0, 0);
    __syncthreads();   // drains vmcnt(0): tile 0 ready; also covers sc init

    for (int k0 = 0; k0 < Kp; k0 += 32) {
        int cur = (k0 >> 5) & 1;
        int kn  = k0 + 32;
        if (kn < Kp) {   // DMA next tile into buf^1; completes under the MFMAs
            unsigned short* lb = &Ls[cur ^ 1][0];
#pragma unroll
            for (int j = 0; j < 9; j++)
                __builtin_amdgcn_global_load_lds((GASV*)(gp[j] + kn), (LASV*)(lb + lof[j]), 16, 0, 0);
        }

        const unsigned short* Lc = &Ls[cur][0];
        short8 a_h[2], a_l[2];
#pragma unroll
        for (int mt = 0; mt < 2; mt++) {
            int row = wm + mt * 16 + l16;
            int cph = (quad ^ ((row >> 1) & 3)) * 8;
            a_h[mt] = *(const short8*)(Lc + row * 32 + cph);
            a_l[mt] = *(const short8*)(Lc + 2048 + row * 32 + cph);
        }
#pragma unroll
        for (int nt = 0; nt < 7; nt++) {
            int row = wn + nt * 16 + l16;
            int cph = (quad ^ ((row >> 1) & 3)) * 8;
            short8 b_h = *(const short8*)(Lc + 4096 + row * 32 + cph);
            short8 b_l = *(const short8*)(Lc + 11264 + row * 32 + cph);
#pragma unroll
            for (int mt = 0; mt < 2; mt++) {
                acc[mt][nt] = __builtin_amdgcn_mfma_f32_16x16x32_bf16(a_h[mt], b_h, acc[mt][nt], 0, 0, 0);
                acc[mt][nt] = __builtin_amdgcn_mfma_f32_16x16x32_bf16(a_h[mt], b_l, acc[mt][nt], 0, 0, 0);
                acc[mt][nt] = __builtin_amdgcn_mfma_f32_16x16x32_bf16(a_l[mt], b_h, acc[mt][nt], 0, 0, 0);
            }
        }
        __syncthreads();   // readers done + next tile's DMA drained (vmcnt 0)
    }

    // per-lane per-nt score weights (uniform loads, cached)
    float asc[7], adc[7];
    bool  vld[7];
    bool  hd1[7];
#pragma unroll
    for (int nt = 0; nt < 7; nt++) {
        int col = wn + nt * 16 + l16;
        vld[nt] = col < HC;
        hd1[nt] = col >= Cch;
        asc[nt] = vld[nt] ? asrc[col] : 0.f;
        adc[nt] = vld[nt] ? adst[col] : 0.f;
    }

    // epilogue: write h + accumulate score partials
#pragma unroll
    for (int mt = 0; mt < 2; mt++) {
        float p[4][4];
#pragma unroll
        for (int r = 0; r < 4; r++)
#pragma unroll
            for (int t = 0; t < 4; t++) p[r][t] = 0.f;
#pragma unroll
        for (int nt = 0; nt < 7; nt++) {
            int col = wn + nt * 16 + l16;
#pragma unroll
            for (int r = 0; r < 4; r++) {
                float v = acc[mt][nt][r];
                int grow = r0 + wm + mt * 16 + quad * 4 + r;
                if (vld[nt] && grow < M) h[(size_t)grow * HC + col] = v;
                float va = v * asc[nt], vd = v * adc[nt];
                p[r][0] += hd1[nt] ? 0.f : va;
                p[r][1] += hd1[nt] ? va  : 0.f;
                p[r][2] += hd1[nt] ? 0.f : vd;
                p[r][3] += hd1[nt] ? vd  : 0.f;
            }
        }
#pragma unroll
        for (int off = 1; off < 16; off <<= 1)
#pragma unroll
            for (int r = 0; r < 4; r++)
#pragma unroll
                for (int t = 0; t < 4; t++)
                    p[r][t] += __shfl_xor(p[r][t], off);
        if (l16 == 0) {
            int lrow = wm + mt * 16 + quad * 4;
#pragma unroll
            for (int r = 0; r < 4; r++)
#pragma unroll
                for (int t = 0; t < 4; t++)
                    atomicAdd(&sc[lrow + r][t], p[r][t]);
        }
    }
    __syncthreads();
    if (tid < 64) {
        int grow = r0 + tid;
        bool v = grow < M;
        // R14: OOB rows now hold garbage (clamped DMA) -> exclude from max
        float e0v = v ? sc[tid][0] : -INFINITY;
        float e1v = v ? sc[tid][1] : -INFINITY;
        if (v) {
            es[grow * 2 + 0] = e0v;
            es[grow * 2 + 1] = e1v;
            ed[grow * 2 + 0] = sc[tid][2];
            ed[grow * 2 + 1] = sc[tid][3];
        }
#pragma unroll
        for (int off = 1; off < 64; off <<= 1) {
            e0v = fmaxf(e0v, __shfl_xor(e0v, off));
            e1v = fmaxf(e1v, __shfl_xor(e1v, off));
        }
        if (tid == 0) {
            atomicMax(&gmax[0], enc_f32(e0v));
            atomicMax(&gmax[1], enc_f32(e1v));
        }
    }
}

// ---------------- fused softmax + weighted gather (wave per dst node) ----------------
// R12: SINGLE pass. Instead of a per-node max pass, use the per-layer global
// es-max: m_node <= leaky(es_gmax + ed_node) (leaky is monotone), and a softmax
// shift by any upper bound leaves alpha = p/sum(p) unchanged. p <= 1 guaranteed;
// sum(p) shrinks by exp(m_true - bound) ~ e^-few, so epsilon lowered to 1e-33.
// (R5 lesson: shfls in uniform control flow only.)
template<bool WF, bool WB>
__global__ __launch_bounds__(256) void gat_gather(
    const float* __restrict__ h, const float* __restrict__ es, const float* __restrict__ ed,
    const unsigned int* __restrict__ gmax,
    const int* __restrict__ row_ptr, const int* __restrict__ col_src,
    const float* __restrict__ bias, float* __restrict__ outF,
    unsigned short* __restrict__ oh, unsigned short* __restrict__ ol, int n_nodes)
{
    int wave = threadIdx.x >> 6, lane = threadIdx.x & 63;
    int n = blockIdx.x * 4 + wave;
    if (n >= n_nodes) return;
    int e0 = row_ptr[n], e1 = row_ptr[n + 1];
    bool act  = lane < 50;
    int  hsel = (lane >= 25) ? 1 : 0;
    float ed0 = ed[n * 2], ed1 = ed[n * 2 + 1];
    float gm0 = dec_f32(gmax[0]), gm1 = dec_f32(gmax[1]);
    float t0 = gm0 + ed0, t1 = gm1 + ed1;
    float mb0 = t0 > 0.f ? t0 : SLOPE * t0;   // upper bound on per-node max
    float mb1 = t1 > 0.f ? t1 : SLOPE * t1;

    // ---- single pass: p = exp(s-mb), accumulate l, gather with unnormalized p ----
    float l0 = 0.f, l1 = 0.f;
    float4v a0 = {0.f, 0.f, 0.f, 0.f}, a1 = {0.f, 0.f, 0.f, 0.f};
    float4v a2 = {0.f, 0.f, 0.f, 0.f}, a3 = {0.f, 0.f, 0.f, 0.f};

    for (int cbase = e0; cbase < e1; cbase += 64) {
        int cnt = e1 - cbase; if (cnt > 64) cnt = 64;
        int   sidx = 0;
        float px = 0.f, py = 0.f;
        if (lane < cnt) {
            sidx = col_src[cbase + lane];
            float2v q = *(const float2v*)&es[sidx * 2];
            float s0 = q.x + ed0, s1 = q.y + ed1;
            s0 = s0 > 0.f ? s0 : SLOPE * s0;
            s1 = s1 > 0.f ? s1 : SLOPE * s1;
            px = __expf(s0 - mb0);
            py = __expf(s1 - mb1);
            l0 += px; l1 += py;
        }
        int j = 0;
        for (; j + 4 <= cnt; j += 4) {
            int s0 = __shfl(sidx, j + 0), s1 = __shfl(sidx, j + 1);
            int s2 = __shfl(sidx, j + 2), s3 = __shfl(sidx, j + 3);
            float x0 = __shfl(px, j + 0), y0 = __shfl(py, j + 0);
            float x1 = __shfl(px, j + 1), y1 = __shfl(py, j + 1);
            float x2 = __shfl(px, j + 2), y2 = __shfl(py, j + 2);
            float x3 = __shfl(px, j + 3), y3 = __shfl(py, j + 3);
            float p0 = hsel ? y0 : x0;
            float p1 = hsel ? y1 : x1;
            float p2 = hsel ? y2 : x2;
            float p3 = hsel ? y3 : x3;
            if (act) {
                float4v v0 = *(const float4v*)(h + (size_t)s0 * HC + lane * 4);
                float4v v1 = *(const float4v*)(h + (size_t)s1 * HC + lane * 4);
                float4v v2 = *(const float4v*)(h + (size_t)s2 * HC + lane * 4);
                float4v v3 = *(const float4v*)(h + (size_t)s3 * HC + lane * 4);
                a0.x += p0 * v0.x; a0.y += p0 * v0.y; a0.z += p0 * v0.z; a0.w += p0 * v0.w;
                a1.x += p1 * v1.x; a1.y += p1 * v1.y; a1.z += p1 * v1.z; a1.w += p1 * v1.w;
                a2.x += p2 * v2.x; a2.y += p2 * v2.y; a2.z += p2 * v2.z; a2.w += p2 * v2.w;
                a3.x += p3 * v3.x; a3.y += p3 * v3.y; a3.z += p3 * v3.z; a3.w += p3 * v3.w;
            }
        }
        for (; j < cnt; j++) {
            int s0 = __shfl(sidx, j);
            float x0 = __shfl(px, j), y0 = __shfl(py, j);
            float p0 = hsel ? y0 : x0;
            if (act) {
                float4v v0 = *(const float4v*)(h + (size_t)s0 * HC + lane * 4);
                a0.x += p0 * v0.x; a0.y += p0 * v0.y; a0.z += p0 * v0.z; a0.w += p0 * v0.w;
            }
        }
    }
#pragma unroll
    for (int off = 1; off < 64; off <<= 1) {
        l0 += __shfl_xor(l0, off);
        l1 += __shfl_xor(l1, off);
    }

    float4v acc;
    acc.x = (a0.x + a1.x) + (a2.x + a3.x);
    acc.y = (a0.y + a1.y) + (a2.y + a3.y);
    acc.z = (a0.z + a1.z) + (a2.z + a3.z);
    acc.w = (a0.w + a1.w) + (a2.w + a3.w);

    float li = 1.f / ((hsel ? l1 : l0) + 1e-33f);
    if (act) {
        float4v bb = *(const float4v*)(bias + lane * 4);
        float4v r;
        r.x = fmaxf(acc.x * li + bb.x, 0.f);
        r.y = fmaxf(acc.y * li + bb.y, 0.f);
        r.z = fmaxf(acc.z * li + bb.z, 0.f);
        r.w = fmaxf(acc.w * li + bb.w, 0.f);
        if (WF) {
            __builtin_nontemporal_store(r, (float4v*)(outF + (size_t)n * HC + lane * 4));
        }
        if (WB) {
            ushort4v hv, lv;
            split_bf(r.x, ((unsigned short*)&hv)[0], ((unsigned short*)&lv)[0]);
            split_bf(r.y, ((unsigned short*)&hv)[1], ((unsigned short*)&lv)[1]);
            split_bf(r.z, ((unsigned short*)&hv)[2], ((unsigned short*)&lv)[2]);
            split_bf(r.w, ((unsigned short*)&hv)[3], ((unsigned short*)&lv)[3]);
            size_t b = (size_t)n * NPAD + lane * 4;
            __builtin_nontemporal_store(hv, (ushort4v*)(oh + b));
            __builtin_nontemporal_store(lv, (ushort4v*)(ol + b));
        }
    } else if (WB && lane < 56) {   // zero pad cols 200..223
        ushort4v z = {0, 0, 0, 0};
        size_t b = (size_t)n * NPAD + lane * 4;
        __builtin_nontemporal_store(z, (ushort4v*)(oh + b));
        __builtin_nontemporal_store(z, (ushort4v*)(ol + b));
    }
}

// ---------------- pooling ----------------
// graph_bounds + pool_zero merged (independent index ranges, one grid) (R11)
__global__ void bounds_zero(const int* __restrict__ batch, int* gstart,
                            float* pool, int n, int g) {
    int i = blockIdx.x * 256 + threadIdx.x;
    if (i < g * HC) pool[i] = 0.f;
    if (i >= n) return;
    int b = batch[i];
    int bp = (i == 0) ? -1 : batch[i - 1];
    for (int q = bp + 1; q <= b; q++) gstart[q] = i;
    if (i == n - 1) for (int q = b + 1; q <= g; q++) gstart[q] = n;
}

__global__ __launch_bounds__(256) void pool_part(
    const float* __restrict__ x, const int* __restrict__ batch,
    float* __restrict__ pool, int n_nodes)
{
    int wave = threadIdx.x >> 6, lane = threadIdx.x & 63;
    int base = (blockIdx.x * 4 + wave) * 16;
    if (base >= n_nodes) return;
    bool act = lane < 50;
    int end = base + 16; if (end > n_nodes) end = n_nodes;
    float4v acc = {0.f, 0.f, 0.f, 0.f};
    int curg = batch[base];
    for (int n = base; n < end; n++) {
        int g = batch[n];
        if (g != curg) {
            if (act) {
                float* pp = pool + (size_t)curg * HC + lane * 4;
                atomicAdd(pp + 0, acc.x); atomicAdd(pp + 1, acc.y);
                atomicAdd(pp + 2, acc.z); atomicAdd(pp + 3, acc.w);
            }
            acc = (float4v){0.f, 0.f, 0.f, 0.f};
            curg = g;
        }
        if (act) {
            float4v v = *(const float4v*)(x + (size_t)n * HC + lane * 4);
            acc.x += v.x; acc.y += v.y; acc.z += v.z; acc.w += v.w;
        }
    }
    if (act) {
        float* pp = pool + (size_t)curg * HC + lane * 4;
        atomicAdd(pp + 0, acc.x); atomicAdd(pp + 1, acc.y);
        atomicAdd(pp + 2, acc.z); atomicAdd(pp + 3, acc.w);
    }
}

// ---------------- fused MLP head: pool-divide + 3 layers, one dispatch (R11) ----------------
__global__ __launch_bounds__(128) void mlp_head(
    const float* __restrict__ pool, const int* __restrict__ gstart,
    const float* __restrict__ lw1, const float* __restrict__ lb1,
    const float* __restrict__ lw2, const float* __restrict__ lb2,
    const float* __restrict__ lw3, const float* __restrict__ lb3,
    float* __restrict__ out)
{
    __shared__ float xa[200];
    __shared__ float xb[100];
    __shared__ float xc[100];
    int g = blockIdx.x, t = threadIdx.x;
    float inv = 1.f / fmaxf((float)(gstart[g + 1] - gstart[g]), 1.f);
    for (int k = t; k < 200; k += 128) xa[k] = pool[g * 200 + k] * inv;
    __syncthreads();
    if (t < 100) {
        float s = lb1[t];
        for (int k = 0; k < 200; k++) s = fmaf(xa[k], lw1[k * 100 + t], s);
        xb[t] = fmaxf(s, 0.f);
    }
    __syncthreads();
    if (t < 100) {
        float s = lb2[t];
        for (int k = 0; k < 100; k++) s = fmaf(xb[k], lw2[k * 100 + t], s);
        xc[t] = fmaxf(s, 0.f);
    }
    __syncthreads();
    if (t < 29) {
        float s = lb3[t];
        for (int k = 0; k < 100; k++) s = fmaf(xc[k], lw3[k * 29 + t], s);
        out[g * 29 + t] = s;
    }
}

// ---------------- launch ----------------
extern "C" void kernel_launch(void* const* d_in, const int* in_sizes, int n_in,
                              void* d_out, int out_size, void* d_ws, size_t ws_size,
                              hipStream_t stream) {
    const float* x     = (const float*)d_in[0];
    const int*   ei    = (const int*)d_in[1];
    const int*   batch = (const int*)d_in[2];
    const float *W[5], *asrc[5], *adst[5], *bc[5];
    for (int i = 0; i < 5; i++) {
        W[i]    = (const float*)d_in[3 + i * 4];
        asrc[i] = (const float*)d_in[4 + i * 4];
        adst[i] = (const float*)d_in[5 + i * 4];
        bc[i]   = (const float*)d_in[6 + i * 4];
    }
    const float* lw1 = (const float*)d_in[23];
    const float* lb1 = (const float*)d_in[24];
    const float* lw2 = (const float*)d_in[25];
    const float* lb2 = (const float*)d_in[26];
    const float* lw3 = (const float*)d_in[27];
    const float* lb3 = (const float*)d_in[28];
    float* out = (float*)d_out;

    const int N  = in_sizes[0] / F_IN;
    const int E  = in_sizes[1] / 2;
    const int G  = out_size / 29;
    const int TE = E + N;
    const int* esrc = ei;
    const int* edst = ei + E;

    const int WSZ0 = NPAD * KP0;          // layer-0 split-weight size
    const int WSZ  = NPAD * KP1;          // layers 1-4
    const int WTOT = WSZ0 + 4 * WSZ;

    // workspace carve
    char* p = (char*)d_ws;
    auto carve = [&](size_t bytes) { void* r = (void*)p; p += ((bytes + 255) / 256) * 256; return r; };
    float*          hbuf = (float*)carve((size_t)N * HC * 4);          // GEMM out h (fp32)
    unsigned short* Ah   = (unsigned short*)carve((size_t)N * KP0 * 2);
    unsigned short* Al   = (unsigned short*)carve((size_t)N * KP0 * 2);
    float*          outF = (float*)Ah;  // aliases Ah/Al (dead by the time L5 gather writes)
    unsigned short* Wth  = (unsigned short*)carve((size_t)WTOT * 2);
    unsigned short* Wtl  = (unsigned short*)carve((size_t)WTOT * 2);
    float* es_     = (float*)carve((size_t)N * 2 * 4);
    float* ed_     = (float*)carve((size_t)N * 2 * 4);
    unsigned int* gmax5 = (unsigned int*)carve(10 * 4);   // 5 layers x 2 heads es-max
    int*   deg     = (int*)carve((size_t)N * 4);
    int*   incl    = (int*)carve((size_t)N * 4);
    int*   bsums   = (int*)carve(SCAN_BS * 4);
    int*   row_ptr = (int*)carve((size_t)(N + 1) * 4);
    int*   cursor  = (int*)carve((size_t)N * 4);
    int*   col_src = (int*)carve((size_t)TE * 4);
    int*   gstart  = (int*)carve((size_t)(G + 1) * 4);
    float* pool    = (float*)carve((size_t)G * HC * 4);

    const int nBlkN   = (N + 255) / 256;
    const int nBlkE   = (E + 255) / 256;
    const int nBlkTE  = (TE + 255) / 256;
    const int nScanB  = (N + SCAN_BS - 1) / SCAN_BS;
    const int nWaveB  = (N + 3) / 4;
    const int nGemmB  = (N + 63) / 64;
    const int nPoolB  = (N + 63) / 64;
    const int nBZ     = (((N > G * HC) ? N : G * HC) + 255) / 256;

    // ---- CSR build ----
    init_deg<<<nBlkN, 256, 0, stream>>>(deg, gmax5, N);
    count_deg<<<nBlkE, 256, 0, stream>>>(edst, deg, E);
    scan_block<<<nScanB, SCAN_BS, 0, stream>>>(deg, incl, bsums, N);
    scan_sums<<<1, SCAN_BS, 0, stream>>>(bsums, nScanB);
    scan_final<<<nScanB, SCAN_BS, 0, stream>>>(incl, deg, bsums, row_ptr, cursor, N);
    fill_csr<<<nBlkTE, 256, 0, stream>>>(esrc, edst, cursor, col_src, E, N);

    // ---- input + weight splits (once) ----
    conv_x<<<(N * (KP0 / 4) + 255) / 256, 256, 0, stream>>>(x, Ah, Al, N);
    conv_w_all<<<(WTOT + 255) / 256, 256, 0, stream>>>(W[0], W[1], W[2], W[3], W[4], Wth, Wtl);

    // ---- 5 GAT layers ----
    for (int L = 0; L < 5; L++) {
        int Kp   = (L == 0) ? KP0 : KP1;
        int woff = (L == 0) ? 0 : WSZ0 + (L - 1) * WSZ;
        gemm_split<<<nGemmB, 256, 0, stream>>>(Ah, Al, Wth + woff, Wtl + woff,
                                               asrc[L], adst[L], hbuf, es_, ed_,
                                               gmax5 + 2 * L, N, Kp);
        if (L < 4)
            gat_gather<false, true><<<nWaveB, 256, 0, stream>>>(hbuf, es_, ed_, gmax5 + 2 * L,
                                                                row_ptr, col_src,
                                                                bc[L], nullptr, Ah, Al, N);
        else
            gat_gather<true, false><<<nWaveB, 256, 0, stream>>>(hbuf, es_, ed_, gmax5 + 2 * L,
                                                                row_ptr, col_src,
                                                                bc[L], outF, nullptr, nullptr, N);
    }

    // ---- pooling + MLP head ----
    bounds_zero<<<nBZ, 256, 0, stream>>>(batch, gstart, pool, N, G);
    pool_part<<<nPoolB, 256, 0, stream>>>(outF, batch, pool, N);
    mlp_head<<<G, 128, 0, stream>>>(pool, gstart, lw1, lb1, lw2, lb2, lw3, lb3, out);
}